// Round 4
// baseline (300.124 us; speedup 1.0000x reference)
//
#include <hip/hip_runtime.h>
#include <stdint.h>

// Problem constants
#define T_DIM 512
#define B_DIM 128
#define DIN   512
#define H_DIM 1024
#define M_DIM (T_DIM * B_DIM)          // 65536
#define OUT_ELEMS 67108864             // M_DIM * H_DIM

typedef __attribute__((ext_vector_type(8))) short bf16x8;
typedef __attribute__((ext_vector_type(4))) float f32x4;
typedef unsigned short u16;

static __device__ __forceinline__ u16 f2bf(float f) {
    union { float f; uint32_t u; } v; v.f = f;
    uint32_t u = v.u;
    uint32_t r = (u + 0x7FFFu + ((u >> 16) & 1u)) >> 16;   // RNE
    return (u16)r;
}

typedef const __attribute__((address_space(1))) void GASV;
typedef __attribute__((address_space(3))) void LASV;
static __device__ __forceinline__ void gload_lds16(const void* g, void* l) {
    __builtin_amdgcn_global_load_lds((GASV*)g, (LASV*)l, 16, 0, 0);
}

#define SB0()   __builtin_amdgcn_sched_barrier(0)
#define BAR()   do { __builtin_amdgcn_s_barrier(); SB0(); } while (0)
#define LGKM0() do { asm volatile("s_waitcnt lgkmcnt(0)" ::: "memory"); SB0(); } while (0)
#define VM0()   do { asm volatile("s_waitcnt vmcnt(0)" ::: "memory"); SB0(); } while (0)

// ---------------------------------------------------------------------------
// Kernel 1: convert x, W_in, W_h, hidden to bf16 (8 elems/thread);
//           copy hidden f32 to d_out tail.
// ---------------------------------------------------------------------------
__global__ __launch_bounds__(256) void k_convert(
    const float* __restrict__ x, const float* __restrict__ W_in,
    const float* __restrict__ W_h, const float* __restrict__ hidden,
    u16* __restrict__ x_bf, u16* __restrict__ Win_bf,
    u16* __restrict__ Wh_bf, u16* __restrict__ hid_bf,
    float* __restrict__ out_hidden)
{
    int u = blockIdx.x * 256 + threadIdx.x;
    const float* src; u16* dst; int i;
    if (u < 4194304)      { i = u;           src = x;      dst = x_bf;   }
    else if (u < 4259840) { i = u - 4194304; src = W_in;   dst = Win_bf; }
    else if (u < 4390912) { i = u - 4259840; src = W_h;    dst = Wh_bf;  }
    else                  { i = u - 4390912; src = hidden; dst = hid_bf; }
    float4 v0 = reinterpret_cast<const float4*>(src)[2 * (size_t)i];
    float4 v1 = reinterpret_cast<const float4*>(src)[2 * (size_t)i + 1];
    union { bf16x8 v; u16 s[8]; } r;
    r.s[0] = f2bf(v0.x); r.s[1] = f2bf(v0.y);
    r.s[2] = f2bf(v0.z); r.s[3] = f2bf(v0.w);
    r.s[4] = f2bf(v1.x); r.s[5] = f2bf(v1.y);
    r.s[6] = f2bf(v1.z); r.s[7] = f2bf(v1.w);
    reinterpret_cast<bf16x8*>(dst)[i] = r.v;
    if (u >= 4390912) {   // second tuple output: hidden verbatim
        reinterpret_cast<float4*>(out_hidden)[2 * i]     = v0;
        reinterpret_cast<float4*>(out_hidden)[2 * i + 1] = v1;
    }
}

// ---------------------------------------------------------------------------
// Kernel 2: bias2[b][h] = hidden @ W_h^T + b_h + b_in   (128 x 1024, K=1024)
// ---------------------------------------------------------------------------
__global__ __launch_bounds__(256, 2) void k_bias2(
    const u16* __restrict__ hid_bf, const u16* __restrict__ Wh_bf,
    const float* __restrict__ b_in, const float* __restrict__ b_h,
    float* __restrict__ bias2)
{
    __shared__ alignas(16) char lds[16384];     // A: [0,8192) B: [8192,16384)
    const int tid = threadIdx.x;
    const int mt = blockIdx.x & 1, nt = blockIdx.x >> 1;   // 2 x 16 tiles
    const int m0 = mt * 64, n0 = nt * 64;
    const int l = tid & 63, w = tid >> 6;
    const int wm = w >> 1, wn = w & 1;
    const int r = l & 15, q = l >> 4;

    f32x4 acc[2][2] = {};

    for (int kb = 0; kb < 1024; kb += 64) {
        __syncthreads();
        #pragma unroll
        for (int i = 0; i < 2; ++i) {
            int idx = tid + i * 256;            // 0..511 : 64 rows x 8 chunks
            int row = idx >> 3, koff = (idx & 7) * 8;
            int off = (row * 128 + koff * 2) ^ ((row & 7) << 4);
            bf16x8 av = *reinterpret_cast<const bf16x8*>(&hid_bf[(m0 + row) * 1024 + kb + koff]);
            *reinterpret_cast<bf16x8*>(&lds[off]) = av;
            bf16x8 bv = *reinterpret_cast<const bf16x8*>(&Wh_bf[(n0 + row) * 1024 + kb + koff]);
            *reinterpret_cast<bf16x8*>(&lds[8192 + off]) = bv;
        }
        __syncthreads();
        #pragma unroll
        for (int kk = 0; kk < 2; ++kk) {
            bf16x8 a[2], b[2];
            #pragma unroll
            for (int mi = 0; mi < 2; ++mi) {
                int row = wm * 32 + mi * 16 + r;
                int off = (row * 128 + kk * 64 + q * 16) ^ ((row & 7) << 4);
                a[mi] = *reinterpret_cast<const bf16x8*>(&lds[off]);
            }
            #pragma unroll
            for (int ni = 0; ni < 2; ++ni) {
                int row = wn * 32 + ni * 16 + r;
                int off = 8192 + ((row * 128 + kk * 64 + q * 16) ^ ((row & 7) << 4));
                b[ni] = *reinterpret_cast<const bf16x8*>(&lds[off]);
            }
            #pragma unroll
            for (int mi = 0; mi < 2; ++mi)
                #pragma unroll
                for (int ni = 0; ni < 2; ++ni)
                    acc[mi][ni] = __builtin_amdgcn_mfma_f32_16x16x32_bf16(
                        a[mi], b[ni], acc[mi][ni], 0, 0, 0);
        }
    }
    #pragma unroll
    for (int mi = 0; mi < 2; ++mi)
        #pragma unroll
        for (int ni = 0; ni < 2; ++ni)
            #pragma unroll
            for (int reg = 0; reg < 4; ++reg) {
                int brow = m0 + wm * 32 + mi * 16 + q * 4 + reg;
                int col  = n0 + wn * 32 + ni * 16 + r;
                bias2[brow * 1024 + col] = acc[mi][ni][reg] + b_in[col] + b_h[col];
            }
}

// ---------------------------------------------------------------------------
// Kernel 3: main GEMM — 256x256x(BK=64) 8-phase schedule (m201-style).
//   512 threads = 8 waves (2M x 4N), 128x64 out per wave.
//   LDS: A,B each 2 x 32KB dbuf = 128 KiB. XOR-swizzle via pre-swizzled src.
//   Tile k+1's 8 gload_lds burst at phase 0 of tile k (4-phase lead);
//   vmcnt(0) only at phase 3 — loads in flight across 7 barriers (T4).
//   4 phases/K-tile: {ds_read subtile; bar; lgkm(0); setprio 16xMFMA; bar}.
// ---------------------------------------------------------------------------
__global__ __launch_bounds__(512, 2) void k_main(
    const u16* __restrict__ x_bf,         // [65536][512] bf16
    const u16* __restrict__ Win_bf,       // [1024][512] bf16
    const float* __restrict__ bias2,      // [128][1024]
    const float* __restrict__ hidden,     // [128][1024]
    float* __restrict__ out)              // [65536][1024]
{
    __shared__ alignas(16) char ldsA[2][32768];   // 256 rows x 64 bf16, swizzled
    __shared__ alignas(16) char ldsB[2][32768];

    const int tid = threadIdx.x;
    const int bid = (int)blockIdx.x;
    // XCD-bijective swizzle: nwg=1024, 1024%8==0, cpx=128
    const int wgid = (bid & 7) * 128 + (bid >> 3);
    const int nt = wgid & 3, mt = wgid >> 2;      // 4 n-tiles, 256 m-tiles
    const int m0 = mt * 256, n0 = nt * 256;

    const int l = tid & 63, w = tid >> 6;         // 8 waves
    const int wm = w >> 2, wn = w & 3;            // 2M x 4N
    const int r = l & 15, q = (l >> 4) & 3;
    const int swz = (r & 7) << 4;                 // row&7 == r&7 for all frags

    // staging: thread t covers slots t+i*512 (i=0..3) per operand
    const int rbase = tid >> 3;                   // 0..63
    const int cs = (tid & 7) ^ (rbase & 7);       // pre-swizzled source chunk
    const int soff = cs * 8;                      // element offset in 64-row

    // fragment LDS byte bases (within a 32KB buffer)
    const int aBase = (wm * 128 + r) * 128 + q * 16;   // + mi*2048 + kk*64
    const int bBase = (wn * 64 + r) * 128 + q * 16;    // + ni*2048 + kk*64

    f32x4 acc[8][4] = {};

    // ---------------- prologue: stage tile 0 into buf 0 ----------------
    #pragma unroll
    for (int i = 0; i < 4; ++i) {
        const int row = rbase + i * 64;
        gload_lds16(&x_bf[(size_t)(m0 + row) * 512 + soff],
                    &ldsA[0][(tid + i * 512) * 16]);
        gload_lds16(&Win_bf[(size_t)(n0 + row) * 512 + soff],
                    &ldsB[0][(tid + i * 512) * 16]);
    }
    VM0();
    BAR();

    // ---------------- main loop: 8 K-tiles ----------------
    #pragma unroll 2
    for (int kt = 0; kt < 8; ++kt) {
        const int cur = kt & 1;
        const char* bufA = &ldsA[cur][0];
        const char* bufB = &ldsB[cur][0];
        bf16x8 a[4], b[4];

        // ================= phase 0: kk=0, mi 0-3 (+B kk0, +stage k+1) ====
        #pragma unroll
        for (int mi = 0; mi < 4; ++mi)
            a[mi] = *reinterpret_cast<const bf16x8*>(bufA + ((aBase + mi * 2048) ^ swz));
        #pragma unroll
        for (int ni = 0; ni < 4; ++ni)
            b[ni] = *reinterpret_cast<const bf16x8*>(bufB + ((bBase + ni * 2048) ^ swz));
        if (kt < 7) {
            const int nxt = cur ^ 1;
            #pragma unroll
            for (int i = 0; i < 4; ++i) {
                const int row = rbase + i * 64;
                gload_lds16(&x_bf[(size_t)(m0 + row) * 512 + (kt + 1) * 64 + soff],
                            &ldsA[nxt][(tid + i * 512) * 16]);
                gload_lds16(&Win_bf[(size_t)(n0 + row) * 512 + (kt + 1) * 64 + soff],
                            &ldsB[nxt][(tid + i * 512) * 16]);
            }
        }
        SB0();
        BAR();
        LGKM0();
        __builtin_amdgcn_s_setprio(1);
        #pragma unroll
        for (int mi = 0; mi < 4; ++mi)
            #pragma unroll
            for (int ni = 0; ni < 4; ++ni)
                acc[mi][ni] = __builtin_amdgcn_mfma_f32_16x16x32_bf16(
                    b[ni], a[mi], acc[mi][ni], 0, 0, 0);
        __builtin_amdgcn_s_setprio(0);
        SB0();
        BAR();

        // ================= phase 1: kk=0, mi 4-7 (reuse b) ===============
        #pragma unroll
        for (int mi = 0; mi < 4; ++mi)
            a[mi] = *reinterpret_cast<const bf16x8*>(bufA + ((aBase + (mi + 4) * 2048) ^ swz));
        SB0();
        BAR();
        LGKM0();
        __builtin_amdgcn_s_setprio(1);
        #pragma unroll
        for (int mi = 0; mi < 4; ++mi)
            #pragma unroll
            for (int ni = 0; ni < 4; ++ni)
                acc[mi + 4][ni] = __builtin_amdgcn_mfma_f32_16x16x32_bf16(
                    b[ni], a[mi], acc[mi + 4][ni], 0, 0, 0);
        __builtin_amdgcn_s_setprio(0);
        SB0();
        BAR();

        // ================= phase 2: kk=1, mi 0-3 (+B kk1) ================
        #pragma unroll
        for (int mi = 0; mi < 4; ++mi)
            a[mi] = *reinterpret_cast<const bf16x8*>(bufA + ((aBase + mi * 2048 + 64) ^ swz));
        #pragma unroll
        for (int ni = 0; ni < 4; ++ni)
            b[ni] = *reinterpret_cast<const bf16x8*>(bufB + ((bBase + ni * 2048 + 64) ^ swz));
        SB0();
        BAR();
        LGKM0();
        __builtin_amdgcn_s_setprio(1);
        #pragma unroll
        for (int mi = 0; mi < 4; ++mi)
            #pragma unroll
            for (int ni = 0; ni < 4; ++ni)
                acc[mi][ni] = __builtin_amdgcn_mfma_f32_16x16x32_bf16(
                    b[ni], a[mi], acc[mi][ni], 0, 0, 0);
        __builtin_amdgcn_s_setprio(0);
        SB0();
        BAR();

        // ================= phase 3: kk=1, mi 4-7 (+vmcnt(0) at end) ======
        #pragma unroll
        for (int mi = 0; mi < 4; ++mi)
            a[mi] = *reinterpret_cast<const bf16x8*>(bufA + ((aBase + (mi + 4) * 2048 + 64) ^ swz));
        SB0();
        BAR();
        LGKM0();
        __builtin_amdgcn_s_setprio(1);
        #pragma unroll
        for (int mi = 0; mi < 4; ++mi)
            #pragma unroll
            for (int ni = 0; ni < 4; ++ni)
                acc[mi + 4][ni] = __builtin_amdgcn_mfma_f32_16x16x32_bf16(
                    b[ni], a[mi], acc[mi + 4][ni], 0, 0, 0);
        __builtin_amdgcn_s_setprio(0);
        SB0();
        VM0();     // tile k+1 fully landed (issued 4 phases ago)
        BAR();
    }

    // ---------------- epilogue: out = 0.9*hidden + 0.1*relu(acc+bias2) ----
    #pragma unroll
    for (int mi = 0; mi < 8; ++mi) {
        const int m = m0 + wm * 128 + mi * 16 + r;
        const int bb_ = m & 127;               // m = t*128 + b
        #pragma unroll
        for (int ni = 0; ni < 4; ++ni) {
            const int n = n0 + wn * 64 + ni * 16 + q * 4;
            float4 bb = *reinterpret_cast<const float4*>(&bias2[bb_ * 1024 + n]);
            float4 hh = *reinterpret_cast<const float4*>(&hidden[bb_ * 1024 + n]);
            f32x4 v = acc[mi][ni];
            float4 o;
            o.x = 0.9f * hh.x + 0.1f * fmaxf(v[0] + bb.x, 0.0f);
            o.y = 0.9f * hh.y + 0.1f * fmaxf(v[1] + bb.y, 0.0f);
            o.z = 0.9f * hh.z + 0.1f * fmaxf(v[2] + bb.z, 0.0f);
            o.w = 0.9f * hh.w + 0.1f * fmaxf(v[3] + bb.w, 0.0f);
            *reinterpret_cast<float4*>(&out[(size_t)m * 1024 + n]) = o;
        }
    }
}

// ---------------------------------------------------------------------------
extern "C" void kernel_launch(void* const* d_in, const int* in_sizes, int n_in,
                              void* d_out, int out_size, void* d_ws, size_t ws_size,
                              hipStream_t stream) {
    const float* x      = (const float*)d_in[0];
    const float* hidden = (const float*)d_in[1];
    const float* W_in   = (const float*)d_in[2];
    const float* b_in   = (const float*)d_in[3];
    const float* W_h    = (const float*)d_in[4];
    const float* b_h    = (const float*)d_in[5];
    float* out = (float*)d_out;

    char* ws = (char*)d_ws;                    // needs ~71 MiB of scratch
    u16*   x_bf   = (u16*)  (ws + 0);          // 64 MiB
    u16*   Win_bf = (u16*)  (ws + 67108864);   // 1 MiB
    u16*   Wh_bf  = (u16*)  (ws + 68157440);   // 2 MiB
    u16*   hid_bf = (u16*)  (ws + 70254592);   // 256 KiB
    float* bias2  = (float*)(ws + 70516736);   // 512 KiB

    float* out_hidden = out + OUT_ELEMS;       // tuple output 1: hidden

    k_convert<<<17216, 256, 0, stream>>>(x, W_in, W_h, hidden,
                                         x_bf, Win_bf, Wh_bf, hid_bf, out_hidden);
    k_bias2<<<32, 256, 0, stream>>>(hid_bf, Wh_bf, b_in, b_h, bias2);
    k_main<<<1024, 512, 0, stream>>>(x_bf, Win_bf, bias2, hidden, out);
}

// Round 5
// 219.782 us; speedup vs baseline: 1.3656x; 1.3656x over previous
//
#include <hip/hip_runtime.h>
#include <stdint.h>

// Problem constants
#define T_DIM 512
#define B_DIM 128
#define DIN   512
#define H_DIM 1024
#define M_DIM (T_DIM * B_DIM)          // 65536
#define OUT_ELEMS 67108864             // M_DIM * H_DIM

typedef __attribute__((ext_vector_type(8))) short bf16x8;
typedef __attribute__((ext_vector_type(4))) float f32x4;
typedef unsigned short u16;

static __device__ __forceinline__ u16 f2bf(float f) {
    union { float f; uint32_t u; } v; v.f = f;
    uint32_t u = v.u;
    uint32_t r = (u + 0x7FFFu + ((u >> 16) & 1u)) >> 16;   // RNE
    return (u16)r;
}

typedef const __attribute__((address_space(1))) void GASV;
typedef __attribute__((address_space(3))) void LASV;
static __device__ __forceinline__ void gload_lds16(const void* g, void* l) {
    __builtin_amdgcn_global_load_lds((GASV*)g, (LASV*)l, 16, 0, 0);
}

// ---------------------------------------------------------------------------
// Kernel 1: convert x, W_in, W_h, hidden to bf16 (8 elems/thread);
//           copy hidden f32 to d_out tail.
// ---------------------------------------------------------------------------
__global__ __launch_bounds__(256) void k_convert(
    const float* __restrict__ x, const float* __restrict__ W_in,
    const float* __restrict__ W_h, const float* __restrict__ hidden,
    u16* __restrict__ x_bf, u16* __restrict__ Win_bf,
    u16* __restrict__ Wh_bf, u16* __restrict__ hid_bf,
    float* __restrict__ out_hidden)
{
    int u = blockIdx.x * 256 + threadIdx.x;
    const float* src; u16* dst; int i;
    if (u < 4194304)      { i = u;           src = x;      dst = x_bf;   }
    else if (u < 4259840) { i = u - 4194304; src = W_in;   dst = Win_bf; }
    else if (u < 4390912) { i = u - 4259840; src = W_h;    dst = Wh_bf;  }
    else                  { i = u - 4390912; src = hidden; dst = hid_bf; }
    float4 v0 = reinterpret_cast<const float4*>(src)[2 * (size_t)i];
    float4 v1 = reinterpret_cast<const float4*>(src)[2 * (size_t)i + 1];
    union { bf16x8 v; u16 s[8]; } r;
    r.s[0] = f2bf(v0.x); r.s[1] = f2bf(v0.y);
    r.s[2] = f2bf(v0.z); r.s[3] = f2bf(v0.w);
    r.s[4] = f2bf(v1.x); r.s[5] = f2bf(v1.y);
    r.s[6] = f2bf(v1.z); r.s[7] = f2bf(v1.w);
    reinterpret_cast<bf16x8*>(dst)[i] = r.v;
    if (u >= 4390912) {   // second tuple output: hidden verbatim
        reinterpret_cast<float4*>(out_hidden)[2 * i]     = v0;
        reinterpret_cast<float4*>(out_hidden)[2 * i + 1] = v1;
    }
}

// ---------------------------------------------------------------------------
// Kernel 2: bias2[b][h] = hidden @ W_h^T + b_h + b_in   (128 x 1024, K=1024)
// ---------------------------------------------------------------------------
__global__ __launch_bounds__(256, 2) void k_bias2(
    const u16* __restrict__ hid_bf, const u16* __restrict__ Wh_bf,
    const float* __restrict__ b_in, const float* __restrict__ b_h,
    float* __restrict__ bias2)
{
    __shared__ alignas(16) char lds[16384];     // A: [0,8192) B: [8192,16384)
    const int tid = threadIdx.x;
    const int mt = blockIdx.x & 1, nt = blockIdx.x >> 1;   // 2 x 16 tiles
    const int m0 = mt * 64, n0 = nt * 64;
    const int l = tid & 63, w = tid >> 6;
    const int wm = w >> 1, wn = w & 1;
    const int r = l & 15, q = l >> 4;

    f32x4 acc[2][2] = {};

    for (int kb = 0; kb < 1024; kb += 64) {
        __syncthreads();
        #pragma unroll
        for (int i = 0; i < 2; ++i) {
            int idx = tid + i * 256;            // 0..511 : 64 rows x 8 chunks
            int row = idx >> 3, koff = (idx & 7) * 8;
            int off = (row * 128 + koff * 2) ^ ((row & 7) << 4);
            bf16x8 av = *reinterpret_cast<const bf16x8*>(&hid_bf[(m0 + row) * 1024 + kb + koff]);
            *reinterpret_cast<bf16x8*>(&lds[off]) = av;
            bf16x8 bv = *reinterpret_cast<const bf16x8*>(&Wh_bf[(n0 + row) * 1024 + kb + koff]);
            *reinterpret_cast<bf16x8*>(&lds[8192 + off]) = bv;
        }
        __syncthreads();
        #pragma unroll
        for (int kk = 0; kk < 2; ++kk) {
            bf16x8 a[2], b[2];
            #pragma unroll
            for (int mi = 0; mi < 2; ++mi) {
                int row = wm * 32 + mi * 16 + r;
                int off = (row * 128 + kk * 64 + q * 16) ^ ((row & 7) << 4);
                a[mi] = *reinterpret_cast<const bf16x8*>(&lds[off]);
            }
            #pragma unroll
            for (int ni = 0; ni < 2; ++ni) {
                int row = wn * 32 + ni * 16 + r;
                int off = 8192 + ((row * 128 + kk * 64 + q * 16) ^ ((row & 7) << 4));
                b[ni] = *reinterpret_cast<const bf16x8*>(&lds[off]);
            }
            #pragma unroll
            for (int mi = 0; mi < 2; ++mi)
                #pragma unroll
                for (int ni = 0; ni < 2; ++ni)
                    acc[mi][ni] = __builtin_amdgcn_mfma_f32_16x16x32_bf16(
                        a[mi], b[ni], acc[mi][ni], 0, 0, 0);
        }
    }
    #pragma unroll
    for (int mi = 0; mi < 2; ++mi)
        #pragma unroll
        for (int ni = 0; ni < 2; ++ni)
            #pragma unroll
            for (int reg = 0; reg < 4; ++reg) {
                int brow = m0 + wm * 32 + mi * 16 + q * 4 + reg;
                int col  = n0 + wn * 32 + ni * 16 + r;
                bias2[brow * 1024 + col] = acc[mi][ni][reg] + b_in[col] + b_h[col];
            }
}

// ---------------------------------------------------------------------------
// Kernel 3: main GEMM — 128x128xBK64, double-buffered, ONE sync per K-step.
//   Per iteration: __syncthreads() [drains stage(t), all prev reads done]
//                  -> issue stage(t+1) into other buffer (8 gload_lds)
//                  -> ds_read buf[t] + 32 MFMA  (covers stage(t+1) latency)
//   LDS 64 KiB -> 2 blocks/CU. XOR-swizzle via pre-swizzled source (G21).
//   Swapped-operand MFMA -> float4 epilogue.
// ---------------------------------------------------------------------------
__global__ __launch_bounds__(256, 2) void k_main(
    const u16* __restrict__ x_bf,         // [65536][512] bf16
    const u16* __restrict__ Win_bf,       // [1024][512] bf16
    const float* __restrict__ bias2,      // [128][1024]
    const float* __restrict__ hidden,     // [128][1024]
    float* __restrict__ out)              // [65536][1024]
{
    __shared__ alignas(16) char ldsA[2][16384];  // 128 rows x 64 bf16, swizzled
    __shared__ alignas(16) char ldsB[2][16384];

    const int tid = threadIdx.x;
    const int bid = (int)blockIdx.x;
    // XCD-bijective swizzle: nwg=4096, 4096%8==0, cpx=512
    const int wgid = (bid & 7) * 512 + (bid >> 3);
    const int nt = wgid & 7, mt = wgid >> 3;
    const int m0 = mt * 128, n0 = nt * 128;
    const int l = tid & 63, w = tid >> 6;
    const int wm = w >> 1, wn = w & 1;          // 2x2 waves, 64x64 each
    const int r = l & 15, q = l >> 4;

    // staging: wave w stages segs w*4..w*4+3; seg = 8 rows x 8 chunks(16B)
    const int rs = l >> 3;                      // row within segment (=row&7)
    const int ck = (l & 7) ^ rs;                // pre-swizzled source chunk

    f32x4 acc[4][4] = {};

    // -------- prologue: stage tile 0 into buffer 0 --------
    #pragma unroll
    for (int j = 0; j < 4; ++j) {
        const int seg = w * 4 + j;
        const int row = seg * 8 + rs;
        gload_lds16(&x_bf[(size_t)(m0 + row) * 512 + ck * 8],
                    &ldsA[0][seg * 1024]);
        gload_lds16(&Win_bf[(size_t)(n0 + row) * 512 + ck * 8],
                    &ldsB[0][seg * 1024]);
    }

    // -------- main loop: 8 K-steps of 64 --------
    #pragma unroll
    for (int k = 0; k < 8; ++k) {
        const int cur = k & 1;
        // vmcnt(0)+lgkmcnt(0)+barrier: stage(k) landed everywhere,
        // and every wave finished reading buf[cur^1] (prev step).
        __syncthreads();

        if (k < 7) {
            const int nxt = cur ^ 1;
            #pragma unroll
            for (int j = 0; j < 4; ++j) {
                const int seg = w * 4 + j;
                const int row = seg * 8 + rs;
                gload_lds16(&x_bf[(size_t)(m0 + row) * 512 + (k + 1) * 64 + ck * 8],
                            &ldsA[nxt][seg * 1024]);
                gload_lds16(&Win_bf[(size_t)(n0 + row) * 512 + (k + 1) * 64 + ck * 8],
                            &ldsB[nxt][seg * 1024]);
            }
        }

        #pragma unroll
        for (int kk = 0; kk < 2; ++kk) {
            bf16x8 a[4], b[4];
            #pragma unroll
            for (int mi = 0; mi < 4; ++mi) {
                int row = wm * 64 + mi * 16 + r;
                int off = (row * 128 + kk * 64 + q * 16) ^ ((row & 7) << 4);
                a[mi] = *reinterpret_cast<const bf16x8*>(&ldsA[cur][off]);
            }
            #pragma unroll
            for (int ni = 0; ni < 4; ++ni) {
                int row = wn * 64 + ni * 16 + r;
                int off = (row * 128 + kk * 64 + q * 16) ^ ((row & 7) << 4);
                b[ni] = *reinterpret_cast<const bf16x8*>(&ldsB[cur][off]);
            }
            // swapped operands: lane (q,r): m = base_m + r, regs = 4 consec n
            #pragma unroll
            for (int mi = 0; mi < 4; ++mi)
                #pragma unroll
                for (int ni = 0; ni < 4; ++ni)
                    acc[mi][ni] = __builtin_amdgcn_mfma_f32_16x16x32_bf16(
                        b[ni], a[mi], acc[mi][ni], 0, 0, 0);
        }
    }

    // ---- epilogue: out = 0.9*hidden + 0.1*relu(acc + bias2), float4-wide ----
    #pragma unroll
    for (int mi = 0; mi < 4; ++mi) {
        const int m = m0 + wm * 64 + mi * 16 + r;
        const int b = m & 127;                  // m = t*128 + b
        #pragma unroll
        for (int ni = 0; ni < 4; ++ni) {
            const int n = n0 + wn * 64 + ni * 16 + q * 4;
            float4 bb = *reinterpret_cast<const float4*>(&bias2[b * 1024 + n]);
            float4 hh = *reinterpret_cast<const float4*>(&hidden[b * 1024 + n]);
            f32x4 v = acc[mi][ni];
            float4 o;
            o.x = 0.9f * hh.x + 0.1f * fmaxf(v[0] + bb.x, 0.0f);
            o.y = 0.9f * hh.y + 0.1f * fmaxf(v[1] + bb.y, 0.0f);
            o.z = 0.9f * hh.z + 0.1f * fmaxf(v[2] + bb.z, 0.0f);
            o.w = 0.9f * hh.w + 0.1f * fmaxf(v[3] + bb.w, 0.0f);
            *reinterpret_cast<float4*>(&out[(size_t)m * 1024 + n]) = o;
        }
    }
}

// ---------------------------------------------------------------------------
extern "C" void kernel_launch(void* const* d_in, const int* in_sizes, int n_in,
                              void* d_out, int out_size, void* d_ws, size_t ws_size,
                              hipStream_t stream) {
    const float* x      = (const float*)d_in[0];
    const float* hidden = (const float*)d_in[1];
    const float* W_in   = (const float*)d_in[2];
    const float* b_in   = (const float*)d_in[3];
    const float* W_h    = (const float*)d_in[4];
    const float* b_h    = (const float*)d_in[5];
    float* out = (float*)d_out;

    char* ws = (char*)d_ws;                    // needs ~71 MiB of scratch
    u16*   x_bf   = (u16*)  (ws + 0);          // 64 MiB
    u16*   Win_bf = (u16*)  (ws + 67108864);   // 1 MiB
    u16*   Wh_bf  = (u16*)  (ws + 68157440);   // 2 MiB
    u16*   hid_bf = (u16*)  (ws + 70254592);   // 256 KiB
    float* bias2  = (float*)(ws + 70516736);   // 512 KiB

    float* out_hidden = out + OUT_ELEMS;       // tuple output 1: hidden

    k_convert<<<17216, 256, 0, stream>>>(x, W_in, W_h, hidden,
                                         x_bf, Win_bf, Wh_bf, hid_bf, out_hidden);
    k_bias2<<<32, 256, 0, stream>>>(hid_bf, Wh_bf, b_in, b_h, bias2);
    k_main<<<4096, 256, 0, stream>>>(x_bf, Win_bf, bias2, hidden, out);
}